// Round 9
// baseline (96.568 us; speedup 1.0000x reference)
//
#include <hip/hip_runtime.h>
#include <hip/hip_bf16.h>
#include <stdint.h>

// CA model: B=8, H=256, W=256, C=16, HID=128, steps=2 (fixed by setup_inputs).
// Per step: y=[x,sobel1,sobel2] (48) -> h=relu(y@W0^T+b0) (128) -> dx=h@W1^T (16)
// -> x' = x + dx*mask (channels 3: only). MLP on bf16 MFMA (16x16x32),
// residual/update path in fp32. Mask: JAX threefry2x32 partitionable bits.
// Round 9: residency/overhead lever — (a) bias folded into GEMM1's K-pad
// (k=48 carries b0, B-side 1.0) deleting the 32-VGPR bias4 array; (b) weight
// prologue vectorized to floatx4 loads (~40 VMEM vs ~160 scalar); (c) x-tile
// staging + mask issued before the weight prologue to hide HBM latency.

#define NB 8
#define NH 256
#define NW 256
#define NC 16
#define TH 8
#define TW 32

typedef __attribute__((ext_vector_type(8))) short short8;
typedef __attribute__((ext_vector_type(4))) float floatx4;

__host__ __device__ inline void tf2x32(uint32_t k0, uint32_t k1,
                                       uint32_t x0, uint32_t x1,
                                       uint32_t& o0, uint32_t& o1) {
  const uint32_t ks2 = k0 ^ k1 ^ 0x1BD11BDAu;
  x0 += k0; x1 += k1;
#define RL(v, d) (((v) << (d)) | ((v) >> (32 - (d))))
#define R4(a, b, c, d)                          \
  x0 += x1; x1 = RL(x1, a); x1 ^= x0;           \
  x0 += x1; x1 = RL(x1, b); x1 ^= x0;           \
  x0 += x1; x1 = RL(x1, c); x1 ^= x0;           \
  x0 += x1; x1 = RL(x1, d); x1 ^= x0;
  R4(13, 15, 26, 6);  x0 += k1;  x1 += ks2 + 1u;
  R4(17, 29, 16, 24); x0 += ks2; x1 += k0 + 2u;
  R4(13, 15, 26, 6);  x0 += k0;  x1 += k1 + 3u;
  R4(17, 29, 16, 24); x0 += k1;  x1 += ks2 + 4u;
  R4(13, 15, 26, 6);  x0 += ks2; x1 += k0 + 5u;
#undef R4
#undef RL
  o0 = x0; o1 = x1;
}

__device__ inline short bfr(float x) {
  __hip_bfloat16 h = __float2bfloat16(x);
  return *reinterpret_cast<short*>(&h);
}

__global__ __launch_bounds__(256, 2) void ca_step(
    const float* __restrict__ xin, float* __restrict__ xout,
    const float* __restrict__ W0, const float* __restrict__ b0,
    const float* __restrict__ W1, uint32_t fk0, uint32_t fk1) {
  // fp32 x tile + halo (10 rows x 34 cols), 16B-chunk XOR-swizzled
  __shared__ float xs[10 * 34 * 16];

  const int tid = threadIdx.x;
  const int bt = blockIdx.x;
  const int wt = bt & 7;
  const int htile = (bt >> 3) & 31;
  const int b = bt >> 8;
  const int h0 = htile * TH;
  const int w0 = wt * TW;

  const int lane = tid & 63;
  const int wv = tid >> 6;
  const int c15 = lane & 15;
  const int g = lane >> 4;

  auto xsaddr = [&](int row, int col, int chunk) -> floatx4* {
    const int off = (row * 34 + col) * 64 + ((chunk ^ ((col >> 1) & 3)) << 4);
    return reinterpret_cast<floatx4*>(reinterpret_cast<char*>(xs) + off);
  };

  // ---- stage x tile FIRST (fp32, zero-padded halo, swizzled) so HBM
  // latency hides under the weight prologue ----
  for (int f = tid; f < 10 * 34 * 4; f += 256) {
    const int row = f / 136;
    const int rem = f - row * 136;
    const int col = rem >> 2;
    const int q = rem & 3;
    const int gh = h0 - 1 + row;
    const int gw = w0 - 1 + col;
    floatx4 v = {0.f, 0.f, 0.f, 0.f};
    if ((unsigned)gh < (unsigned)NH && (unsigned)gw < (unsigned)NW)
      v = *reinterpret_cast<const floatx4*>(
          xin + (((size_t)b * NH + gh) * NW + gw) * NC + 4 * q);
    *xsaddr(row, col, q) = v;
  }

  // ---- fire mask: wave wv owns rows 2wv,2wv+1 x 32 cols; bit lane =
  // (rowparity<<5) | col ----
  uint64_t mball;
  {
    const int cellg = (b * NH + h0 + 2 * wv + (lane >> 5)) * NW + w0 + (lane & 31);
    uint32_t r0, r1;
    tf2x32(fk0, fk1, 0u, (uint32_t)cellg, r0, r1);
    const uint32_t bits = r0 ^ r1;
    const float u = __uint_as_float((bits >> 9) | 0x3F800000u) - 1.0f;
    mball = __ballot(u > 0.5f);
  }

  // ---- weight fragments held in VGPRs for whole kernel (vectorized) ----
  // GEMM1': H^T = W0 . Y^T  (A-frag: lane holds A[row=c15][k=8g+j])
  // K-pad trick: A[o][48] = b0[o] (g==2, j==0 slot), B[48][*] = 1.0 -> bias
  // enters via the second MFMA; acc inits to zero, no bias4 registers.
  short8 w0f[8][2];
  short8 w1f[4];
#pragma unroll
  for (int n = 0; n < 8; ++n) {
    const int o = 16 * n + c15;
    const float* p = W0 + o * 48 + 8 * g;
    const floatx4 v0 = *reinterpret_cast<const floatx4*>(p);
    const floatx4 v1 = *reinterpret_cast<const floatx4*>(p + 4);
    short8 f;
    f[0] = bfr(v0.x); f[1] = bfr(v0.y); f[2] = bfr(v0.z); f[3] = bfr(v0.w);
    f[4] = bfr(v1.x); f[5] = bfr(v1.y); f[6] = bfr(v1.z); f[7] = bfr(v1.w);
    w0f[n][0] = f;
    short8 f1;
    if (g < 2) {
      const float* p1 = W0 + o * 48 + 32 + 8 * g;
      const floatx4 u0 = *reinterpret_cast<const floatx4*>(p1);
      const floatx4 u1 = *reinterpret_cast<const floatx4*>(p1 + 4);
      f1[0] = bfr(u0.x); f1[1] = bfr(u0.y); f1[2] = bfr(u0.z); f1[3] = bfr(u0.w);
      f1[4] = bfr(u1.x); f1[5] = bfr(u1.y); f1[6] = bfr(u1.z); f1[7] = bfr(u1.w);
    } else {
#pragma unroll
      for (int j = 0; j < 8; ++j) f1[j] = 0;
      if (g == 2) f1[0] = bfr(b0[o]);   // A[o][48] = b0[o]
    }
    w0f[n][1] = f1;
  }
  // GEMM2': A = W1 [16 ch x 128 o], k-order permuted by tau so the B-frag
  // is the lane's own GEMM1 accumulators: tau(s,8g+j)=32s+16*(j>>2)+4g+(j&3)
  // j&3 runs over contiguous quads -> two floatx4 loads per fragment.
#pragma unroll
  for (int s = 0; s < 4; ++s) {
    const float* p = W1 + c15 * 128 + 32 * s + 4 * g;
    const floatx4 v0 = *reinterpret_cast<const floatx4*>(p);
    const floatx4 v1 = *reinterpret_cast<const floatx4*>(p + 16);
    short8 f;
    f[0] = bfr(v0.x); f[1] = bfr(v0.y); f[2] = bfr(v0.z); f[3] = bfr(v0.w);
    f[4] = bfr(v1.x); f[5] = bfr(v1.y); f[6] = bfr(v1.z); f[7] = bfr(v1.w);
    w1f[s] = f;
  }

  // per-lane sobel tap weights: groups 0/1 produce c2 (sobel2), 2/3 c1 (sobel1)
  float wts[8];
  {
    const float Ac[3] = {1.f, 2.f, 1.f};
    const float Bc[3] = {-1.f, 0.f, 1.f};
    int t = 0;
#pragma unroll
    for (int dh = -1; dh <= 1; ++dh)
#pragma unroll
      for (int dw = -1; dw <= 1; ++dw) {
        if (dh == 0 && dw == 0) continue;
        const float wA = Ac[dw + 1] * Bc[dh + 1] * 0.125f;  // c1
        const float wB = Ac[dh + 1] * Bc[dw + 1] * 0.125f;  // c2
        wts[t++] = (g < 2) ? wB : wA;
      }
  }

  __syncthreads();

  const int cc = 2 * (g & 1);   // chunk pair base for this lane's 8 channels

#pragma unroll
  for (int mt = 0; mt < 4; ++mt) {
    const int rp = mt >> 1;             // row parity within wave's pair
    const int chh = mt & 1;             // col half
    const int r = 1 + 2 * wv + rp;
    const int col = 1 + 16 * chh + c15;

    // center x (identity part of y for groups 0/1)
    const floatx4 xc0 = *xsaddr(r, col, cc);
    const floatx4 xc1 = *xsaddr(r, col, cc + 1);

    // branchless 8-tap sobel over this lane's 8 channels
    float sob[8];
#pragma unroll
    for (int j = 0; j < 8; ++j) sob[j] = 0.f;
    int t = 0;
#pragma unroll
    for (int dh = -1; dh <= 1; ++dh)
#pragma unroll
      for (int dw = -1; dw <= 1; ++dw) {
        if (dh == 0 && dw == 0) continue;
        const floatx4 v0 = *xsaddr(r + dh, col + dw, cc);
        const floatx4 v1 = *xsaddr(r + dh, col + dw, cc + 1);
        const float w = wts[t++];
        sob[0] += w * v0.x; sob[1] += w * v0.y;
        sob[2] += w * v0.z; sob[3] += w * v0.w;
        sob[4] += w * v1.x; sob[5] += w * v1.y;
        sob[6] += w * v1.z; sob[7] += w * v1.w;
      }

    // Y^T B-fragments: a0 -> k 0..31 (x | c1), a1 -> k 32..63 (c2 | bias-1 | 0)
    const bool lo = (g < 2);
    const float xcv[8] = {xc0.x, xc0.y, xc0.z, xc0.w, xc1.x, xc1.y, xc1.z, xc1.w};
    short8 a0, a1;
#pragma unroll
    for (int j = 0; j < 8; ++j) {
      const short sb = bfr(sob[j]);
      a0[j] = lo ? bfr(xcv[j]) : sb;
      a1[j] = lo ? sb : (short)0;
    }
    if (g == 2) a1[0] = bfr(1.0f);   // B[48][cell] = 1 -> adds b0[o]

    // GEMM1': 16 MFMAs -> H^T tiles; lane holds H^T[o=16n+4g+r][cell=c15]
    floatx4 acc[8];
#pragma unroll
    for (int n = 0; n < 8; ++n) acc[n] = floatx4{0.f, 0.f, 0.f, 0.f};
#pragma unroll
    for (int n = 0; n < 8; ++n)
      acc[n] = __builtin_amdgcn_mfma_f32_16x16x32_bf16(w0f[n][0], a0, acc[n], 0, 0, 0);
#pragma unroll
    for (int n = 0; n < 8; ++n)
      acc[n] = __builtin_amdgcn_mfma_f32_16x16x32_bf16(w0f[n][1], a1, acc[n], 0, 0, 0);

    // GEMM2': dx^T = W1 . H with permuted k-order; B-frag is the lane's own
    // relu'd accumulators: b2[j] = bf16(relu(acc[2s + (j>>2)][j&3]))
    floatx4 acc2 = {0.f, 0.f, 0.f, 0.f};
#pragma unroll
    for (int s = 0; s < 4; ++s) {
      short8 b2;
#pragma unroll
      for (int j = 0; j < 8; ++j)
        b2[j] = bfr(fmaxf(acc[2 * s + (j >> 2)][j & 3], 0.f));
      acc2 = __builtin_amdgcn_mfma_f32_16x16x32_bf16(w1f[s], b2, acc2, 0, 0, 0);
    }

    // update: lane holds dx[ch=4g+reg][cell=c15]; fp32 residual path
    const floatx4 xv = *xsaddr(r, col, g);
    const float mk = (float)((mball >> (32 * rp + 16 * chh + c15)) & 1ull);
    const float mk03 = (g == 0) ? 0.f : mk;   // channels 0..2 frozen
    floatx4 ov;
    ov.x = xv.x + acc2.x * mk03;
    ov.y = xv.y + acc2.y * mk03;
    ov.z = xv.z + acc2.z * mk03;
    ov.w = xv.w + acc2.w * mk;
    const size_t cellg =
        ((size_t)(b * NH + h0 + 2 * wv + rp)) * NW + w0 + 16 * chh + c15;
    *reinterpret_cast<floatx4*>(xout + cellg * NC + 4 * g) = ov;
  }
}

extern "C" void kernel_launch(void* const* d_in, const int* in_sizes, int n_in,
                              void* d_out, int out_size, void* d_ws, size_t ws_size,
                              hipStream_t stream) {
  const float* x  = (const float*)d_in[0];
  const float* W0 = (const float*)d_in[1];
  const float* b0 = (const float*)d_in[2];
  const float* W1 = (const float*)d_in[3];
  float* tmp = (float*)d_ws;
  float* out = (float*)d_out;

  uint32_t fa0, fa1, fb0, fb1;
  tf2x32(0u, 42u, 0u, 0u, fa0, fa1);  // fold_in(key(42), 0)
  tf2x32(0u, 42u, 0u, 1u, fb0, fb1);  // fold_in(key(42), 1)

  dim3 grid(NB * (NH / TH) * (NW / TW)), block(256);
  ca_step<<<grid, block, 0, stream>>>(x, tmp, W0, b0, W1, fa0, fa1);
  ca_step<<<grid, block, 0, stream>>>(tmp, out, W0, b0, W1, fb0, fb1);
}

// Round 10
// 83.264 us; speedup vs baseline: 1.1598x; 1.1598x over previous
//
#include <hip/hip_runtime.h>
#include <hip/hip_bf16.h>
#include <stdint.h>

// CA model: B=8, H=256, W=256, C=16, HID=128, steps=2 (fixed by setup_inputs).
// Per step: y=[x,sobel1,sobel2] (48) -> h=relu(y@W0^T+b0) (128) -> dx=h@W1^T (16)
// -> x' = x + dx*mask (channels 3: only). MLP on bf16 MFMA (16x16x32),
// residual/update path in fp32. Mask: JAX threefry2x32 partitionable bits.
// Round 10: block granularity 4 waves -> 1 wave. Tile TH4xTW16 per wave,
// 8192 independent 64-thread blocks, LDS 6.9KB/block, no inter-wave barrier
// coupling. Per-wave compute identical to round-9 (64 cells, same fragments,
// same tau-permuted GEMM2, same K-pad bias).

#define NB 8
#define NH 256
#define NW 256
#define NC 16
#define TH 4
#define TW 16

typedef __attribute__((ext_vector_type(8))) short short8;
typedef __attribute__((ext_vector_type(4))) float floatx4;

__host__ __device__ inline void tf2x32(uint32_t k0, uint32_t k1,
                                       uint32_t x0, uint32_t x1,
                                       uint32_t& o0, uint32_t& o1) {
  const uint32_t ks2 = k0 ^ k1 ^ 0x1BD11BDAu;
  x0 += k0; x1 += k1;
#define RL(v, d) (((v) << (d)) | ((v) >> (32 - (d))))
#define R4(a, b, c, d)                          \
  x0 += x1; x1 = RL(x1, a); x1 ^= x0;           \
  x0 += x1; x1 = RL(x1, b); x1 ^= x0;           \
  x0 += x1; x1 = RL(x1, c); x1 ^= x0;           \
  x0 += x1; x1 = RL(x1, d); x1 ^= x0;
  R4(13, 15, 26, 6);  x0 += k1;  x1 += ks2 + 1u;
  R4(17, 29, 16, 24); x0 += ks2; x1 += k0 + 2u;
  R4(13, 15, 26, 6);  x0 += k0;  x1 += k1 + 3u;
  R4(17, 29, 16, 24); x0 += k1;  x1 += ks2 + 4u;
  R4(13, 15, 26, 6);  x0 += ks2; x1 += k0 + 5u;
#undef R4
#undef RL
  o0 = x0; o1 = x1;
}

__device__ inline short bfr(float x) {
  __hip_bfloat16 h = __float2bfloat16(x);
  return *reinterpret_cast<short*>(&h);
}

__global__ __launch_bounds__(64, 2) void ca_step(
    const float* __restrict__ xin, float* __restrict__ xout,
    const float* __restrict__ W0, const float* __restrict__ b0,
    const float* __restrict__ W1, uint32_t fk0, uint32_t fk1) {
  // fp32 x tile + halo (6 rows x 18 cols), 16B-chunk XOR-swizzled
  __shared__ float xs[6 * 18 * 16];

  const int tid = threadIdx.x;
  const int bt = blockIdx.x;
  const int wt = bt & 15;
  const int htile = (bt >> 4) & 63;
  const int b = bt >> 10;
  const int h0 = htile * TH;
  const int w0 = wt * TW;

  const int lane = tid;
  const int c15 = lane & 15;
  const int g = lane >> 4;

  auto xsaddr = [&](int row, int col, int chunk) -> floatx4* {
    const int off = (row * 18 + col) * 64 + ((chunk ^ ((col >> 1) & 3)) << 4);
    return reinterpret_cast<floatx4*>(reinterpret_cast<char*>(xs) + off);
  };

  // ---- stage x tile FIRST (fp32, zero-padded halo, swizzled) so HBM
  // latency hides under the weight prologue ----
  for (int f = tid; f < 6 * 18 * 4; f += 64) {
    const int row = f / 72;
    const int rem = f - row * 72;
    const int col = rem >> 2;
    const int q = rem & 3;
    const int gh = h0 - 1 + row;
    const int gw = w0 - 1 + col;
    floatx4 v = {0.f, 0.f, 0.f, 0.f};
    if ((unsigned)gh < (unsigned)NH && (unsigned)gw < (unsigned)NW)
      v = *reinterpret_cast<const floatx4*>(
          xin + (((size_t)b * NH + gh) * NW + gw) * NC + 4 * q);
    *xsaddr(row, col, q) = v;
  }

  // ---- fire mask: wave owns 4 rows x 16 cols; lane -> (row=lane>>4,
  // col=lane&15); bit = 16*row + col ----
  uint64_t mball;
  {
    const int cellg = (b * NH + h0 + (lane >> 4)) * NW + w0 + c15;
    uint32_t r0, r1;
    tf2x32(fk0, fk1, 0u, (uint32_t)cellg, r0, r1);
    const uint32_t bits = r0 ^ r1;
    const float u = __uint_as_float((bits >> 9) | 0x3F800000u) - 1.0f;
    mball = __ballot(u > 0.5f);
  }

  // ---- weight fragments held in VGPRs for whole kernel (vectorized) ----
  // GEMM1': H^T = W0 . Y^T  (A-frag: lane holds A[row=c15][k=8g+j])
  // K-pad trick: A[o][48] = b0[o] (g==2, j==0 slot), B[48][*] = 1.0.
  short8 w0f[8][2];
  short8 w1f[4];
#pragma unroll
  for (int n = 0; n < 8; ++n) {
    const int o = 16 * n + c15;
    const float* p = W0 + o * 48 + 8 * g;
    const floatx4 v0 = *reinterpret_cast<const floatx4*>(p);
    const floatx4 v1 = *reinterpret_cast<const floatx4*>(p + 4);
    short8 f;
    f[0] = bfr(v0.x); f[1] = bfr(v0.y); f[2] = bfr(v0.z); f[3] = bfr(v0.w);
    f[4] = bfr(v1.x); f[5] = bfr(v1.y); f[6] = bfr(v1.z); f[7] = bfr(v1.w);
    w0f[n][0] = f;
    short8 f1;
    if (g < 2) {
      const float* p1 = W0 + o * 48 + 32 + 8 * g;
      const floatx4 u0 = *reinterpret_cast<const floatx4*>(p1);
      const floatx4 u1 = *reinterpret_cast<const floatx4*>(p1 + 4);
      f1[0] = bfr(u0.x); f1[1] = bfr(u0.y); f1[2] = bfr(u0.z); f1[3] = bfr(u0.w);
      f1[4] = bfr(u1.x); f1[5] = bfr(u1.y); f1[6] = bfr(u1.z); f1[7] = bfr(u1.w);
    } else {
#pragma unroll
      for (int j = 0; j < 8; ++j) f1[j] = 0;
      if (g == 2) f1[0] = bfr(b0[o]);   // A[o][48] = b0[o]
    }
    w0f[n][1] = f1;
  }
  // GEMM2': A = W1 [16 ch x 128 o], k-order permuted by tau so the B-frag
  // is the lane's own GEMM1 accumulators: tau(s,8g+j)=32s+16*(j>>2)+4g+(j&3)
#pragma unroll
  for (int s = 0; s < 4; ++s) {
    const float* p = W1 + c15 * 128 + 32 * s + 4 * g;
    const floatx4 v0 = *reinterpret_cast<const floatx4*>(p);
    const floatx4 v1 = *reinterpret_cast<const floatx4*>(p + 16);
    short8 f;
    f[0] = bfr(v0.x); f[1] = bfr(v0.y); f[2] = bfr(v0.z); f[3] = bfr(v0.w);
    f[4] = bfr(v1.x); f[5] = bfr(v1.y); f[6] = bfr(v1.z); f[7] = bfr(v1.w);
    w1f[s] = f;
  }

  // per-lane sobel tap weights: groups 0/1 produce c2 (sobel2), 2/3 c1 (sobel1)
  float wts[8];
  {
    const float Ac[3] = {1.f, 2.f, 1.f};
    const float Bc[3] = {-1.f, 0.f, 1.f};
    int t = 0;
#pragma unroll
    for (int dh = -1; dh <= 1; ++dh)
#pragma unroll
      for (int dw = -1; dw <= 1; ++dw) {
        if (dh == 0 && dw == 0) continue;
        const float wA = Ac[dw + 1] * Bc[dh + 1] * 0.125f;  // c1
        const float wB = Ac[dh + 1] * Bc[dw + 1] * 0.125f;  // c2
        wts[t++] = (g < 2) ? wB : wA;
      }
  }

  __syncthreads();   // single-wave block: compiles to a cheap wait

  const int cc = 2 * (g & 1);   // chunk pair base for this lane's 8 channels

#pragma unroll
  for (int mt = 0; mt < 4; ++mt) {
    const int r = 1 + mt;
    const int col = 1 + c15;

    // center x (identity part of y for groups 0/1)
    const floatx4 xc0 = *xsaddr(r, col, cc);
    const floatx4 xc1 = *xsaddr(r, col, cc + 1);

    // branchless 8-tap sobel over this lane's 8 channels
    float sob[8];
#pragma unroll
    for (int j = 0; j < 8; ++j) sob[j] = 0.f;
    int t = 0;
#pragma unroll
    for (int dh = -1; dh <= 1; ++dh)
#pragma unroll
      for (int dw = -1; dw <= 1; ++dw) {
        if (dh == 0 && dw == 0) continue;
        const floatx4 v0 = *xsaddr(r + dh, col + dw, cc);
        const floatx4 v1 = *xsaddr(r + dh, col + dw, cc + 1);
        const float w = wts[t++];
        sob[0] += w * v0.x; sob[1] += w * v0.y;
        sob[2] += w * v0.z; sob[3] += w * v0.w;
        sob[4] += w * v1.x; sob[5] += w * v1.y;
        sob[6] += w * v1.z; sob[7] += w * v1.w;
      }

    // Y^T B-fragments: a0 -> k 0..31 (x | c1), a1 -> k 32..63 (c2 | bias-1 | 0)
    const bool lo = (g < 2);
    const float xcv[8] = {xc0.x, xc0.y, xc0.z, xc0.w, xc1.x, xc1.y, xc1.z, xc1.w};
    short8 a0, a1;
#pragma unroll
    for (int j = 0; j < 8; ++j) {
      const short sb = bfr(sob[j]);
      a0[j] = lo ? bfr(xcv[j]) : sb;
      a1[j] = lo ? sb : (short)0;
    }
    if (g == 2) a1[0] = bfr(1.0f);   // B[48][cell] = 1 -> adds b0[o]

    // GEMM1': 16 MFMAs -> H^T tiles; lane holds H^T[o=16n+4g+r][cell=c15]
    floatx4 acc[8];
#pragma unroll
    for (int n = 0; n < 8; ++n) acc[n] = floatx4{0.f, 0.f, 0.f, 0.f};
#pragma unroll
    for (int n = 0; n < 8; ++n)
      acc[n] = __builtin_amdgcn_mfma_f32_16x16x32_bf16(w0f[n][0], a0, acc[n], 0, 0, 0);
#pragma unroll
    for (int n = 0; n < 8; ++n)
      acc[n] = __builtin_amdgcn_mfma_f32_16x16x32_bf16(w0f[n][1], a1, acc[n], 0, 0, 0);

    // GEMM2': dx^T = W1 . H with permuted k-order; B-frag is the lane's own
    // relu'd accumulators: b2[j] = bf16(relu(acc[2s + (j>>2)][j&3]))
    floatx4 acc2 = {0.f, 0.f, 0.f, 0.f};
#pragma unroll
    for (int s = 0; s < 4; ++s) {
      short8 b2;
#pragma unroll
      for (int j = 0; j < 8; ++j)
        b2[j] = bfr(fmaxf(acc[2 * s + (j >> 2)][j & 3], 0.f));
      acc2 = __builtin_amdgcn_mfma_f32_16x16x32_bf16(w1f[s], b2, acc2, 0, 0, 0);
    }

    // update: lane holds dx[ch=4g+reg][cell=c15]; fp32 residual path
    const floatx4 xv = *xsaddr(r, col, g);
    const float mk = (float)((mball >> (16 * mt + c15)) & 1ull);
    const float mk03 = (g == 0) ? 0.f : mk;   // channels 0..2 frozen
    floatx4 ov;
    ov.x = xv.x + acc2.x * mk03;
    ov.y = xv.y + acc2.y * mk03;
    ov.z = xv.z + acc2.z * mk03;
    ov.w = xv.w + acc2.w * mk;
    const size_t cellg = ((size_t)(b * NH + h0 + mt)) * NW + w0 + c15;
    *reinterpret_cast<floatx4*>(xout + cellg * NC + 4 * g) = ov;
  }
}

extern "C" void kernel_launch(void* const* d_in, const int* in_sizes, int n_in,
                              void* d_out, int out_size, void* d_ws, size_t ws_size,
                              hipStream_t stream) {
  const float* x  = (const float*)d_in[0];
  const float* W0 = (const float*)d_in[1];
  const float* b0 = (const float*)d_in[2];
  const float* W1 = (const float*)d_in[3];
  float* tmp = (float*)d_ws;
  float* out = (float*)d_out;

  uint32_t fa0, fa1, fb0, fb1;
  tf2x32(0u, 42u, 0u, 0u, fa0, fa1);  // fold_in(key(42), 0)
  tf2x32(0u, 42u, 0u, 1u, fb0, fb1);  // fold_in(key(42), 1)

  dim3 grid(NB * (NH / TH) * (NW / TW)), block(64);
  ca_step<<<grid, block, 0, stream>>>(x, tmp, W0, b0, W1, fa0, fa1);
  ca_step<<<grid, block, 0, stream>>>(tmp, out, W0, b0, W1, fb0, fb1);
}

// Round 11
// 70.658 us; speedup vs baseline: 1.3667x; 1.1784x over previous
//
#include <hip/hip_runtime.h>
#include <hip/hip_bf16.h>
#include <stdint.h>

// CA model: B=8, H=256, W=256, C=16, HID=128, steps=2 (fixed by setup_inputs).
// Per step: y=[x,sobel1,sobel2] (48) -> h=relu(y@W0^T+b0) (128) -> dx=h@W1^T (16)
// -> x' = x + dx*mask (channels 3: only). MLP on bf16 MFMA (16x16x32),
// residual/update path in fp32. Mask: JAX threefry2x32 partitionable bits.
// Round 11: per-wave fixed-overhead lever. (a) ca_prep kernel pre-converts
// W0/b0/W1 into per-lane bf16 fragments in d_ws ([frag][lane] coalesced);
// ca_step<true> loads 20 b128 frags, zero cvt VALU. (b) 2 vertically-adjacent
// tiles per wave (4096 blocks, double-buffered xs) amortizing prologue.
// mt-loop body identical to round-10 passing kernel.

#define NB 8
#define NH 256
#define NW 256
#define NC 16
#define TH 4
#define TW 16
#define WOFF 65536   // tmp offset in d_ws when prep region in use (20.5KB used)

typedef __attribute__((ext_vector_type(8))) short short8;
typedef __attribute__((ext_vector_type(4))) float floatx4;

__host__ __device__ inline void tf2x32(uint32_t k0, uint32_t k1,
                                       uint32_t x0, uint32_t x1,
                                       uint32_t& o0, uint32_t& o1) {
  const uint32_t ks2 = k0 ^ k1 ^ 0x1BD11BDAu;
  x0 += k0; x1 += k1;
#define RL(v, d) (((v) << (d)) | ((v) >> (32 - (d))))
#define R4(a, b, c, d)                          \
  x0 += x1; x1 = RL(x1, a); x1 ^= x0;           \
  x0 += x1; x1 = RL(x1, b); x1 ^= x0;           \
  x0 += x1; x1 = RL(x1, c); x1 ^= x0;           \
  x0 += x1; x1 = RL(x1, d); x1 ^= x0;
  R4(13, 15, 26, 6);  x0 += k1;  x1 += ks2 + 1u;
  R4(17, 29, 16, 24); x0 += ks2; x1 += k0 + 2u;
  R4(13, 15, 26, 6);  x0 += k0;  x1 += k1 + 3u;
  R4(17, 29, 16, 24); x0 += k1;  x1 += ks2 + 4u;
  R4(13, 15, 26, 6);  x0 += ks2; x1 += k0 + 5u;
#undef R4
#undef RL
  o0 = x0; o1 = x1;
}

__device__ inline short bfr(float x) {
  __hip_bfloat16 h = __float2bfloat16(x);
  return *reinterpret_cast<short*>(&h);
}

// ---- one-block prep: per-lane weight fragments -> d_ws ([frag][lane]) ----
__global__ __launch_bounds__(64) void ca_prep(
    const float* __restrict__ W0, const float* __restrict__ b0,
    const float* __restrict__ W1, short* __restrict__ wbuf) {
  const int lane = threadIdx.x;
  const int c15 = lane & 15;
  const int g = lane >> 4;
  short8* wf = reinterpret_cast<short8*>(wbuf);

#pragma unroll
  for (int n = 0; n < 8; ++n) {
    const int o = 16 * n + c15;
    const float* p = W0 + o * 48 + 8 * g;
    const floatx4 v0 = *reinterpret_cast<const floatx4*>(p);
    const floatx4 v1 = *reinterpret_cast<const floatx4*>(p + 4);
    short8 f;
    f[0] = bfr(v0.x); f[1] = bfr(v0.y); f[2] = bfr(v0.z); f[3] = bfr(v0.w);
    f[4] = bfr(v1.x); f[5] = bfr(v1.y); f[6] = bfr(v1.z); f[7] = bfr(v1.w);
    wf[(2 * n) * 64 + lane] = f;
    short8 f1;
    if (g < 2) {
      const float* p1 = W0 + o * 48 + 32 + 8 * g;
      const floatx4 u0 = *reinterpret_cast<const floatx4*>(p1);
      const floatx4 u1 = *reinterpret_cast<const floatx4*>(p1 + 4);
      f1[0] = bfr(u0.x); f1[1] = bfr(u0.y); f1[2] = bfr(u0.z); f1[3] = bfr(u0.w);
      f1[4] = bfr(u1.x); f1[5] = bfr(u1.y); f1[6] = bfr(u1.z); f1[7] = bfr(u1.w);
    } else {
#pragma unroll
      for (int j = 0; j < 8; ++j) f1[j] = 0;
      if (g == 2) f1[0] = bfr(b0[o]);   // A[o][48] = b0[o] (K-pad bias)
    }
    wf[(2 * n + 1) * 64 + lane] = f1;
  }
  // GEMM2' fragments, tau(s,8g+j)=32s+16*(j>>2)+4g+(j&3)
#pragma unroll
  for (int s = 0; s < 4; ++s) {
    const float* p = W1 + c15 * 128 + 32 * s + 4 * g;
    const floatx4 v0 = *reinterpret_cast<const floatx4*>(p);
    const floatx4 v1 = *reinterpret_cast<const floatx4*>(p + 16);
    short8 f;
    f[0] = bfr(v0.x); f[1] = bfr(v0.y); f[2] = bfr(v0.z); f[3] = bfr(v0.w);
    f[4] = bfr(v1.x); f[5] = bfr(v1.y); f[6] = bfr(v1.z); f[7] = bfr(v1.w);
    wf[(16 + s) * 64 + lane] = f;
  }
}

template <bool PRE>
__global__ __launch_bounds__(64, 2) void ca_step(
    const float* __restrict__ xin, float* __restrict__ xout,
    const float* __restrict__ W0, const float* __restrict__ b0,
    const float* __restrict__ W1, const short* __restrict__ wfrag,
    uint32_t fk0, uint32_t fk1) {
  // two fp32 x tiles + halo (6 rows x 18 cols each), 16B-chunk XOR-swizzled
  __shared__ float xs[2][6 * 18 * 16];

  const int tid = threadIdx.x;
  const int bt = blockIdx.x;
  const int wt = bt & 15;
  const int ht8 = (bt >> 4) & 31;
  const int b = bt >> 9;
  const int h0 = ht8 * 8;
  const int w0 = wt * TW;

  const int lane = tid;
  const int c15 = lane & 15;
  const int g = lane >> 4;

  auto xsaddr = [&](float* base, int row, int col, int chunk) -> floatx4* {
    const int off = (row * 18 + col) * 64 + ((chunk ^ ((col >> 1) & 3)) << 4);
    return reinterpret_cast<floatx4*>(reinterpret_cast<char*>(base) + off);
  };

  // ---- weight fragments, loaded once per wave ----
  short8 w0f[8][2];
  short8 w1f[4];
  if constexpr (PRE) {
    const short8* wf = reinterpret_cast<const short8*>(wfrag);
#pragma unroll
    for (int n = 0; n < 8; ++n) {
      w0f[n][0] = wf[(2 * n) * 64 + lane];
      w0f[n][1] = wf[(2 * n + 1) * 64 + lane];
    }
#pragma unroll
    for (int s = 0; s < 4; ++s) w1f[s] = wf[(16 + s) * 64 + lane];
  } else {
#pragma unroll
    for (int n = 0; n < 8; ++n) {
      const int o = 16 * n + c15;
      const float* p = W0 + o * 48 + 8 * g;
      const floatx4 v0 = *reinterpret_cast<const floatx4*>(p);
      const floatx4 v1 = *reinterpret_cast<const floatx4*>(p + 4);
      short8 f;
      f[0] = bfr(v0.x); f[1] = bfr(v0.y); f[2] = bfr(v0.z); f[3] = bfr(v0.w);
      f[4] = bfr(v1.x); f[5] = bfr(v1.y); f[6] = bfr(v1.z); f[7] = bfr(v1.w);
      w0f[n][0] = f;
      short8 f1;
      if (g < 2) {
        const float* p1 = W0 + o * 48 + 32 + 8 * g;
        const floatx4 u0 = *reinterpret_cast<const floatx4*>(p1);
        const floatx4 u1 = *reinterpret_cast<const floatx4*>(p1 + 4);
        f1[0] = bfr(u0.x); f1[1] = bfr(u0.y); f1[2] = bfr(u0.z); f1[3] = bfr(u0.w);
        f1[4] = bfr(u1.x); f1[5] = bfr(u1.y); f1[6] = bfr(u1.z); f1[7] = bfr(u1.w);
      } else {
#pragma unroll
        for (int j = 0; j < 8; ++j) f1[j] = 0;
        if (g == 2) f1[0] = bfr(b0[o]);
      }
      w0f[n][1] = f1;
    }
#pragma unroll
    for (int s = 0; s < 4; ++s) {
      const float* p = W1 + c15 * 128 + 32 * s + 4 * g;
      const floatx4 v0 = *reinterpret_cast<const floatx4*>(p);
      const floatx4 v1 = *reinterpret_cast<const floatx4*>(p + 16);
      short8 f;
      f[0] = bfr(v0.x); f[1] = bfr(v0.y); f[2] = bfr(v0.z); f[3] = bfr(v0.w);
      f[4] = bfr(v1.x); f[5] = bfr(v1.y); f[6] = bfr(v1.z); f[7] = bfr(v1.w);
      w1f[s] = f;
    }
  }

  // per-lane sobel tap weights: groups 0/1 produce c2 (sobel2), 2/3 c1 (sobel1)
  float wts[8];
  {
    const float Ac[3] = {1.f, 2.f, 1.f};
    const float Bc[3] = {-1.f, 0.f, 1.f};
    int t = 0;
#pragma unroll
    for (int dh = -1; dh <= 1; ++dh)
#pragma unroll
      for (int dw = -1; dw <= 1; ++dw) {
        if (dh == 0 && dw == 0) continue;
        const float wA = Ac[dw + 1] * Bc[dh + 1] * 0.125f;  // c1
        const float wB = Ac[dh + 1] * Bc[dw + 1] * 0.125f;  // c2
        wts[t++] = (g < 2) ? wB : wA;
      }
  }

  const int cc = 2 * (g & 1);   // chunk pair base for this lane's 8 channels

#pragma unroll 1
  for (int t2 = 0; t2 < 2; ++t2) {
    const int h0t = h0 + TH * t2;
    float* xsb = xs[t2];

    // ---- stage x tile (fp32, zero-padded halo, swizzled) ----
    for (int f = tid; f < 6 * 18 * 4; f += 64) {
      const int row = f / 72;
      const int rem = f - row * 72;
      const int col = rem >> 2;
      const int q = rem & 3;
      const int gh = h0t - 1 + row;
      const int gw = w0 - 1 + col;
      floatx4 v = {0.f, 0.f, 0.f, 0.f};
      if ((unsigned)gh < (unsigned)NH && (unsigned)gw < (unsigned)NW)
        v = *reinterpret_cast<const floatx4*>(
            xin + (((size_t)b * NH + gh) * NW + gw) * NC + 4 * q);
      *xsaddr(xsb, row, col, q) = v;
    }

    // ---- fire mask: lane -> (row=lane>>4, col=lane&15), bit = 16*row+col ----
    uint64_t mball;
    {
      const int cellg = (b * NH + h0t + (lane >> 4)) * NW + w0 + c15;
      uint32_t r0, r1;
      tf2x32(fk0, fk1, 0u, (uint32_t)cellg, r0, r1);
      const uint32_t bits = r0 ^ r1;
      const float u = __uint_as_float((bits >> 9) | 0x3F800000u) - 1.0f;
      mball = __ballot(u > 0.5f);
    }
    __syncthreads();   // single-wave: drains staging before reads

#pragma unroll
    for (int mt = 0; mt < 4; ++mt) {
      const int r = 1 + mt;
      const int col = 1 + c15;

      // center x (identity part of y for groups 0/1)
      const floatx4 xc0 = *xsaddr(xsb, r, col, cc);
      const floatx4 xc1 = *xsaddr(xsb, r, col, cc + 1);

      // branchless 8-tap sobel over this lane's 8 channels
      float sob[8];
#pragma unroll
      for (int j = 0; j < 8; ++j) sob[j] = 0.f;
      int t = 0;
#pragma unroll
      for (int dh = -1; dh <= 1; ++dh)
#pragma unroll
        for (int dw = -1; dw <= 1; ++dw) {
          if (dh == 0 && dw == 0) continue;
          const floatx4 v0 = *xsaddr(xsb, r + dh, col + dw, cc);
          const floatx4 v1 = *xsaddr(xsb, r + dh, col + dw, cc + 1);
          const float w = wts[t++];
          sob[0] += w * v0.x; sob[1] += w * v0.y;
          sob[2] += w * v0.z; sob[3] += w * v0.w;
          sob[4] += w * v1.x; sob[5] += w * v1.y;
          sob[6] += w * v1.z; sob[7] += w * v1.w;
        }

      // Y^T B-fragments: a0 -> k 0..31 (x | c1), a1 -> k 32..63 (c2|bias|0)
      const bool lo = (g < 2);
      const float xcv[8] = {xc0.x, xc0.y, xc0.z, xc0.w,
                            xc1.x, xc1.y, xc1.z, xc1.w};
      short8 a0, a1;
#pragma unroll
      for (int j = 0; j < 8; ++j) {
        const short sb = bfr(sob[j]);
        a0[j] = lo ? bfr(xcv[j]) : sb;
        a1[j] = lo ? sb : (short)0;
      }
      if (g == 2) a1[0] = bfr(1.0f);   // B[48][cell] = 1 -> adds b0[o]

      // GEMM1': 16 MFMAs; lane holds H^T[o=16n+4g+reg][cell=c15]
      floatx4 acc[8];
#pragma unroll
      for (int n = 0; n < 8; ++n) acc[n] = floatx4{0.f, 0.f, 0.f, 0.f};
#pragma unroll
      for (int n = 0; n < 8; ++n)
        acc[n] = __builtin_amdgcn_mfma_f32_16x16x32_bf16(w0f[n][0], a0, acc[n], 0, 0, 0);
#pragma unroll
      for (int n = 0; n < 8; ++n)
        acc[n] = __builtin_amdgcn_mfma_f32_16x16x32_bf16(w0f[n][1], a1, acc[n], 0, 0, 0);

      // GEMM2': B-frag is the lane's own relu'd accumulators (tau-permuted)
      floatx4 acc2 = {0.f, 0.f, 0.f, 0.f};
#pragma unroll
      for (int s = 0; s < 4; ++s) {
        short8 b2;
#pragma unroll
        for (int j = 0; j < 8; ++j)
          b2[j] = bfr(fmaxf(acc[2 * s + (j >> 2)][j & 3], 0.f));
        acc2 = __builtin_amdgcn_mfma_f32_16x16x32_bf16(w1f[s], b2, acc2, 0, 0, 0);
      }

      // update: lane holds dx[ch=4g+reg][cell=c15]; fp32 residual path
      const floatx4 xv = *xsaddr(xsb, r, col, g);
      const float mk = (float)((mball >> (16 * mt + c15)) & 1ull);
      const float mk03 = (g == 0) ? 0.f : mk;   // channels 0..2 frozen
      floatx4 ov;
      ov.x = xv.x + acc2.x * mk03;
      ov.y = xv.y + acc2.y * mk03;
      ov.z = xv.z + acc2.z * mk03;
      ov.w = xv.w + acc2.w * mk;
      const size_t cellg = ((size_t)(b * NH + h0t + mt)) * NW + w0 + c15;
      *reinterpret_cast<floatx4*>(xout + cellg * NC + 4 * g) = ov;
    }
  }
}

extern "C" void kernel_launch(void* const* d_in, const int* in_sizes, int n_in,
                              void* d_out, int out_size, void* d_ws, size_t ws_size,
                              hipStream_t stream) {
  const float* x  = (const float*)d_in[0];
  const float* W0 = (const float*)d_in[1];
  const float* b0 = (const float*)d_in[2];
  const float* W1 = (const float*)d_in[3];
  float* out = (float*)d_out;

  const size_t tmp_bytes = (size_t)NB * NH * NW * NC * 4;   // 32 MiB
  const bool pre = ws_size >= (size_t)WOFF + tmp_bytes;
  short* wbuf = (short*)d_ws;
  float* tmp = pre ? (float*)((char*)d_ws + WOFF) : (float*)d_ws;

  uint32_t fa0, fa1, fb0, fb1;
  tf2x32(0u, 42u, 0u, 0u, fa0, fa1);  // fold_in(key(42), 0)
  tf2x32(0u, 42u, 0u, 1u, fb0, fb1);  // fold_in(key(42), 1)

  dim3 grid(NB * (NH / 8) * (NW / TW)), block(64);
  if (pre) {
    ca_prep<<<1, 64, 0, stream>>>(W0, b0, W1, wbuf);
    ca_step<true><<<grid, block, 0, stream>>>(x, tmp, W0, b0, W1, wbuf, fa0, fa1);
    ca_step<true><<<grid, block, 0, stream>>>(tmp, out, W0, b0, W1, wbuf, fb0, fb1);
  } else {
    ca_step<false><<<grid, block, 0, stream>>>(x, tmp, W0, b0, W1, nullptr, fa0, fa1);
    ca_step<false><<<grid, block, 0, stream>>>(tmp, out, W0, b0, W1, nullptr, fb0, fb1);
  }
}

// Round 12
// 69.931 us; speedup vs baseline: 1.3809x; 1.0104x over previous
//
#include <hip/hip_runtime.h>
#include <hip/hip_bf16.h>
#include <stdint.h>

// CA model: B=8, H=256, W=256, C=16, HID=128, steps=2 (fixed by setup_inputs).
// Per step: y=[x,sobel1,sobel2] (48) -> h=relu(y@W0^T+b0) (128) -> dx=h@W1^T (16)
// -> x' = x + dx*mask (channels 3: only). MLP on bf16 MFMA (16x16x32),
// residual/update path in fp32. Mask: JAX threefry2x32 partitionable bits.
// Round 12: residency lever at the true binding resource. (a) single xs
// buffer reused across the 2 tiles (LDS 13.8KB -> ~7KB => ~22 blocks/CU cap);
// (b) sobel weights folded to inline consts {0,±1,±2} via 1/8-scaling of
// W0's sobel columns in prep (power-of-2 => bit-identical), deleting wts[8].

#define NB 8
#define NH 256
#define NW 256
#define NC 16
#define TH 4
#define TW 16
#define WOFF 65536   // tmp offset in d_ws when prep region in use

typedef __attribute__((ext_vector_type(8))) short short8;
typedef __attribute__((ext_vector_type(4))) float floatx4;

__host__ __device__ inline void tf2x32(uint32_t k0, uint32_t k1,
                                       uint32_t x0, uint32_t x1,
                                       uint32_t& o0, uint32_t& o1) {
  const uint32_t ks2 = k0 ^ k1 ^ 0x1BD11BDAu;
  x0 += k0; x1 += k1;
#define RL(v, d) (((v) << (d)) | ((v) >> (32 - (d))))
#define R4(a, b, c, d)                          \
  x0 += x1; x1 = RL(x1, a); x1 ^= x0;           \
  x0 += x1; x1 = RL(x1, b); x1 ^= x0;           \
  x0 += x1; x1 = RL(x1, c); x1 ^= x0;           \
  x0 += x1; x1 = RL(x1, d); x1 ^= x0;
  R4(13, 15, 26, 6);  x0 += k1;  x1 += ks2 + 1u;
  R4(17, 29, 16, 24); x0 += ks2; x1 += k0 + 2u;
  R4(13, 15, 26, 6);  x0 += k0;  x1 += k1 + 3u;
  R4(17, 29, 16, 24); x0 += k1;  x1 += ks2 + 4u;
  R4(13, 15, 26, 6);  x0 += ks2; x1 += k0 + 5u;
#undef R4
#undef RL
  o0 = x0; o1 = x1;
}

__device__ inline short bfr(float x) {
  __hip_bfloat16 h = __float2bfloat16(x);
  return *reinterpret_cast<short*>(&h);
}

// ---- one-block prep: per-lane weight fragments -> d_ws ([frag][lane]) ----
// Sobel columns of W0 (c1: k16..31, c2: k32..47) pre-scaled by 1/8 so the
// kernel's tap weights are the inline constants {0,±1,±2}.
__global__ __launch_bounds__(64) void ca_prep(
    const float* __restrict__ W0, const float* __restrict__ b0,
    const float* __restrict__ W1, short* __restrict__ wbuf) {
  const int lane = threadIdx.x;
  const int c15 = lane & 15;
  const int g = lane >> 4;
  short8* wf = reinterpret_cast<short8*>(wbuf);

  const float s0 = (g < 2) ? 1.0f : 0.125f;   // frag0: identity | c1(scaled)
#pragma unroll
  for (int n = 0; n < 8; ++n) {
    const int o = 16 * n + c15;
    const float* p = W0 + o * 48 + 8 * g;
    const floatx4 v0 = *reinterpret_cast<const floatx4*>(p);
    const floatx4 v1 = *reinterpret_cast<const floatx4*>(p + 4);
    short8 f;
    f[0] = bfr(v0.x * s0); f[1] = bfr(v0.y * s0);
    f[2] = bfr(v0.z * s0); f[3] = bfr(v0.w * s0);
    f[4] = bfr(v1.x * s0); f[5] = bfr(v1.y * s0);
    f[6] = bfr(v1.z * s0); f[7] = bfr(v1.w * s0);
    wf[(2 * n) * 64 + lane] = f;
    short8 f1;
    if (g < 2) {   // frag1: c2 columns (scaled)
      const float* p1 = W0 + o * 48 + 32 + 8 * g;
      const floatx4 u0 = *reinterpret_cast<const floatx4*>(p1);
      const floatx4 u1 = *reinterpret_cast<const floatx4*>(p1 + 4);
      f1[0] = bfr(u0.x * 0.125f); f1[1] = bfr(u0.y * 0.125f);
      f1[2] = bfr(u0.z * 0.125f); f1[3] = bfr(u0.w * 0.125f);
      f1[4] = bfr(u1.x * 0.125f); f1[5] = bfr(u1.y * 0.125f);
      f1[6] = bfr(u1.z * 0.125f); f1[7] = bfr(u1.w * 0.125f);
    } else {
#pragma unroll
      for (int j = 0; j < 8; ++j) f1[j] = 0;
      if (g == 2) f1[0] = bfr(b0[o]);   // A[o][48] = b0[o] (K-pad bias)
    }
    wf[(2 * n + 1) * 64 + lane] = f1;
  }
  // GEMM2' fragments, tau(s,8g+j)=32s+16*(j>>2)+4g+(j&3)
#pragma unroll
  for (int s = 0; s < 4; ++s) {
    const float* p = W1 + c15 * 128 + 32 * s + 4 * g;
    const floatx4 v0 = *reinterpret_cast<const floatx4*>(p);
    const floatx4 v1 = *reinterpret_cast<const floatx4*>(p + 16);
    short8 f;
    f[0] = bfr(v0.x); f[1] = bfr(v0.y); f[2] = bfr(v0.z); f[3] = bfr(v0.w);
    f[4] = bfr(v1.x); f[5] = bfr(v1.y); f[6] = bfr(v1.z); f[7] = bfr(v1.w);
    wf[(16 + s) * 64 + lane] = f;
  }
}

template <bool PRE>
__global__ __launch_bounds__(64, 2) void ca_step(
    const float* __restrict__ xin, float* __restrict__ xout,
    const float* __restrict__ W0, const float* __restrict__ b0,
    const float* __restrict__ W1, const short* __restrict__ wfrag,
    uint32_t fk0, uint32_t fk1) {
  // single fp32 x tile + halo (6 rows x 18 cols), 16B-chunk XOR-swizzled,
  // reused across the wave's 2 vertical tiles (WAR ordered by barrier)
  __shared__ float xs[6 * 18 * 16];

  const int tid = threadIdx.x;
  const int bt = blockIdx.x;
  const int wt = bt & 15;
  const int ht8 = (bt >> 4) & 31;
  const int b = bt >> 9;
  const int h0 = ht8 * 8;
  const int w0 = wt * TW;

  const int lane = tid;
  const int c15 = lane & 15;
  const int g = lane >> 4;

  auto xsaddr = [&](int row, int col, int chunk) -> floatx4* {
    const int off = (row * 18 + col) * 64 + ((chunk ^ ((col >> 1) & 3)) << 4);
    return reinterpret_cast<floatx4*>(reinterpret_cast<char*>(xs) + off);
  };

  // ---- weight fragments, loaded once per wave ----
  short8 w0f[8][2];
  short8 w1f[4];
  if constexpr (PRE) {
    const short8* wf = reinterpret_cast<const short8*>(wfrag);
#pragma unroll
    for (int n = 0; n < 8; ++n) {
      w0f[n][0] = wf[(2 * n) * 64 + lane];
      w0f[n][1] = wf[(2 * n + 1) * 64 + lane];
    }
#pragma unroll
    for (int s = 0; s < 4; ++s) w1f[s] = wf[(16 + s) * 64 + lane];
  } else {
    const float s0 = (g < 2) ? 1.0f : 0.125f;
#pragma unroll
    for (int n = 0; n < 8; ++n) {
      const int o = 16 * n + c15;
      const float* p = W0 + o * 48 + 8 * g;
      const floatx4 v0 = *reinterpret_cast<const floatx4*>(p);
      const floatx4 v1 = *reinterpret_cast<const floatx4*>(p + 4);
      short8 f;
      f[0] = bfr(v0.x * s0); f[1] = bfr(v0.y * s0);
      f[2] = bfr(v0.z * s0); f[3] = bfr(v0.w * s0);
      f[4] = bfr(v1.x * s0); f[5] = bfr(v1.y * s0);
      f[6] = bfr(v1.z * s0); f[7] = bfr(v1.w * s0);
      w0f[n][0] = f;
      short8 f1;
      if (g < 2) {
        const float* p1 = W0 + o * 48 + 32 + 8 * g;
        const floatx4 u0 = *reinterpret_cast<const floatx4*>(p1);
        const floatx4 u1 = *reinterpret_cast<const floatx4*>(p1 + 4);
        f1[0] = bfr(u0.x * 0.125f); f1[1] = bfr(u0.y * 0.125f);
        f1[2] = bfr(u0.z * 0.125f); f1[3] = bfr(u0.w * 0.125f);
        f1[4] = bfr(u1.x * 0.125f); f1[5] = bfr(u1.y * 0.125f);
        f1[6] = bfr(u1.z * 0.125f); f1[7] = bfr(u1.w * 0.125f);
      } else {
#pragma unroll
        for (int j = 0; j < 8; ++j) f1[j] = 0;
        if (g == 2) f1[0] = bfr(b0[o]);
      }
      w0f[n][1] = f1;
    }
#pragma unroll
    for (int s = 0; s < 4; ++s) {
      const float* p = W1 + c15 * 128 + 32 * s + 4 * g;
      const floatx4 v0 = *reinterpret_cast<const floatx4*>(p);
      const floatx4 v1 = *reinterpret_cast<const floatx4*>(p + 16);
      short8 f;
      f[0] = bfr(v0.x); f[1] = bfr(v0.y); f[2] = bfr(v0.z); f[3] = bfr(v0.w);
      f[4] = bfr(v1.x); f[5] = bfr(v1.y); f[6] = bfr(v1.z); f[7] = bfr(v1.w);
      w1f[s] = f;
    }
  }

  const int cc = 2 * (g & 1);   // chunk pair base for this lane's 8 channels
  const bool lo = (g < 2);

  // 8x-scaled tap weights (W0 sobel columns carry the 1/8): inline consts.
  // taps t: (dh,dw) = (-1,-1),(-1,0),(-1,1),(0,-1),(0,1),(1,-1),(1,0),(1,1)
  constexpr float WA[8] = {-1.f, -2.f, -1.f, 0.f, 0.f, 1.f, 2.f, 1.f};  // c1
  constexpr float WB[8] = {-1.f, 0.f, 1.f, -2.f, 2.f, -1.f, 0.f, 1.f};  // c2

#pragma unroll 1
  for (int t2 = 0; t2 < 2; ++t2) {
    const int h0t = h0 + TH * t2;

    __syncthreads();   // WAR: prior tile's xs reads drain before re-staging

    // ---- stage x tile (fp32, zero-padded halo, swizzled) ----
    for (int f = tid; f < 6 * 18 * 4; f += 64) {
      const int row = f / 72;
      const int rem = f - row * 72;
      const int col = rem >> 2;
      const int q = rem & 3;
      const int gh = h0t - 1 + row;
      const int gw = w0 - 1 + col;
      floatx4 v = {0.f, 0.f, 0.f, 0.f};
      if ((unsigned)gh < (unsigned)NH && (unsigned)gw < (unsigned)NW)
        v = *reinterpret_cast<const floatx4*>(
            xin + (((size_t)b * NH + gh) * NW + gw) * NC + 4 * q);
      *xsaddr(row, col, q) = v;
    }

    // ---- fire mask: lane -> (row=lane>>4, col=lane&15), bit = 16*row+col ----
    uint64_t mball;
    {
      const int cellg = (b * NH + h0t + (lane >> 4)) * NW + w0 + c15;
      uint32_t r0, r1;
      tf2x32(fk0, fk1, 0u, (uint32_t)cellg, r0, r1);
      const uint32_t bits = r0 ^ r1;
      const float u = __uint_as_float((bits >> 9) | 0x3F800000u) - 1.0f;
      mball = __ballot(u > 0.5f);
    }
    __syncthreads();   // staging drains before reads

#pragma unroll
    for (int mt = 0; mt < 4; ++mt) {
      const int r = 1 + mt;
      const int col = 1 + c15;

      // center x (identity part of y for groups 0/1)
      const floatx4 xc0 = *xsaddr(r, col, cc);
      const floatx4 xc1 = *xsaddr(r, col, cc + 1);

      // branchless 8-tap sobel (8x-scaled weights, inline consts)
      float sob[8];
#pragma unroll
      for (int j = 0; j < 8; ++j) sob[j] = 0.f;
      int t = 0;
#pragma unroll
      for (int dh = -1; dh <= 1; ++dh)
#pragma unroll
        for (int dw = -1; dw <= 1; ++dw) {
          if (dh == 0 && dw == 0) continue;
          const floatx4 v0 = *xsaddr(r + dh, col + dw, cc);
          const floatx4 v1 = *xsaddr(r + dh, col + dw, cc + 1);
          const float w = lo ? WB[t] : WA[t];
          ++t;
          sob[0] += w * v0.x; sob[1] += w * v0.y;
          sob[2] += w * v0.z; sob[3] += w * v0.w;
          sob[4] += w * v1.x; sob[5] += w * v1.y;
          sob[6] += w * v1.z; sob[7] += w * v1.w;
        }

      // Y^T B-fragments: a0 -> k 0..31 (x | c1*8), a1 -> k 32..63 (c2*8|bias|0)
      const float xcv[8] = {xc0.x, xc0.y, xc0.z, xc0.w,
                            xc1.x, xc1.y, xc1.z, xc1.w};
      short8 a0, a1;
#pragma unroll
      for (int j = 0; j < 8; ++j) {
        const short sb = bfr(sob[j]);
        a0[j] = lo ? bfr(xcv[j]) : sb;
        a1[j] = lo ? sb : (short)0;
      }
      if (g == 2) a1[0] = bfr(1.0f);   // B[48][cell] = 1 -> adds b0[o]

      // GEMM1': 16 MFMAs; lane holds H^T[o=16n+4g+reg][cell=c15]
      floatx4 acc[8];
#pragma unroll
      for (int n = 0; n < 8; ++n) acc[n] = floatx4{0.f, 0.f, 0.f, 0.f};
#pragma unroll
      for (int n = 0; n < 8; ++n)
        acc[n] = __builtin_amdgcn_mfma_f32_16x16x32_bf16(w0f[n][0], a0, acc[n], 0, 0, 0);
#pragma unroll
      for (int n = 0; n < 8; ++n)
        acc[n] = __builtin_amdgcn_mfma_f32_16x16x32_bf16(w0f[n][1], a1, acc[n], 0, 0, 0);

      // GEMM2': B-frag is the lane's own relu'd accumulators (tau-permuted)
      floatx4 acc2 = {0.f, 0.f, 0.f, 0.f};
#pragma unroll
      for (int s = 0; s < 4; ++s) {
        short8 b2;
#pragma unroll
        for (int j = 0; j < 8; ++j)
          b2[j] = bfr(fmaxf(acc[2 * s + (j >> 2)][j & 3], 0.f));
        acc2 = __builtin_amdgcn_mfma_f32_16x16x32_bf16(w1f[s], b2, acc2, 0, 0, 0);
      }

      // update: lane holds dx[ch=4g+reg][cell=c15]; fp32 residual path
      const floatx4 xv = *xsaddr(r, col, g);
      const float mk = (float)((mball >> (16 * mt + c15)) & 1ull);
      const float mk03 = (g == 0) ? 0.f : mk;   // channels 0..2 frozen
      floatx4 ov;
      ov.x = xv.x + acc2.x * mk03;
      ov.y = xv.y + acc2.y * mk03;
      ov.z = xv.z + acc2.z * mk03;
      ov.w = xv.w + acc2.w * mk;
      const size_t cellg = ((size_t)(b * NH + h0t + mt)) * NW + w0 + c15;
      *reinterpret_cast<floatx4*>(xout + cellg * NC + 4 * g) = ov;
    }
  }
}

extern "C" void kernel_launch(void* const* d_in, const int* in_sizes, int n_in,
                              void* d_out, int out_size, void* d_ws, size_t ws_size,
                              hipStream_t stream) {
  const float* x  = (const float*)d_in[0];
  const float* W0 = (const float*)d_in[1];
  const float* b0 = (const float*)d_in[2];
  const float* W1 = (const float*)d_in[3];
  float* out = (float*)d_out;

  const size_t tmp_bytes = (size_t)NB * NH * NW * NC * 4;   // 32 MiB
  const bool pre = ws_size >= (size_t)WOFF + tmp_bytes;
  short* wbuf = (short*)d_ws;
  float* tmp = pre ? (float*)((char*)d_ws + WOFF) : (float*)d_ws;

  uint32_t fa0, fa1, fb0, fb1;
  tf2x32(0u, 42u, 0u, 0u, fa0, fa1);  // fold_in(key(42), 0)
  tf2x32(0u, 42u, 0u, 1u, fb0, fb1);  // fold_in(key(42), 1)

  dim3 grid(NB * (NH / 8) * (NW / TW)), block(64);
  if (pre) {
    ca_prep<<<1, 64, 0, stream>>>(W0, b0, W1, wbuf);
    ca_step<true><<<grid, block, 0, stream>>>(x, tmp, W0, b0, W1, wbuf, fa0, fa1);
    ca_step<true><<<grid, block, 0, stream>>>(tmp, out, W0, b0, W1, wbuf, fb0, fb1);
  } else {
    ca_step<false><<<grid, block, 0, stream>>>(x, tmp, W0, b0, W1, nullptr, fa0, fa1);
    ca_step<false><<<grid, block, 0, stream>>>(tmp, out, W0, b0, W1, nullptr, fb0, fb1);
  }
}